// Round 1
// baseline (126.114 us; speedup 1.0000x reference)
//
#include <hip/hip_runtime.h>

#define BATCH 2
#define H 512
#define W 512
#define CS 21
#define CI 3
#define P 64     // pixels per block (one row segment)
#define TPB 256

__device__ __forceinline__ int reflect1(int v, int n) {
    // valid for radius-1 only (np.pad mode='reflect': -1 -> 1, n -> n-2)
    if (v < 0) v = -v;
    else if (v >= n) v = 2 * n - 2 - v;
    return v;
}

__global__ __launch_bounds__(TPB) void jbu_kernel(
    const float* __restrict__ src, const float* __restrict__ im,
    float* __restrict__ out)
{
    __shared__ float s_im[3][P + 2][CI];   // 3 rows x 66 cols x 3 ch = 594 floats
    __shared__ float s_w[P * 9];           // 576 floats
    __shared__ float s_invden[P];          // 64 floats

    const int t  = threadIdx.x;
    const int x0 = blockIdx.x * P;
    const int y  = blockIdx.y;
    const int b  = blockIdx.z;

    const int ry0 = reflect1(y - 1, H);
    const int ry2 = reflect1(y + 1, H);
    const int ryr[3] = { ry0, y, ry2 };

    // ---- Phase 1a: stage guide-image tile (reflect applied here) ----
    for (int i = t; i < 3 * (P + 2) * CI; i += TPB) {
        int r   = i / ((P + 2) * CI);
        int rem = i - r * ((P + 2) * CI);
        int col = rem / CI;
        int ch  = rem - col * CI;
        int gx  = reflect1(x0 + col - 1, W);
        s_im[r][col][ch] = im[((b * H + ryr[r]) * W + gx) * CI + ch];
    }
    __syncthreads();

    // ---- Phase 1b: bilateral * spatial weights, one per (pixel, tap) ----
    const float w1[9] = {0.36787944f, 0.60653066f, 0.36787944f,
                         0.60653066f, 1.0f,        0.60653066f,
                         0.36787944f, 0.60653066f, 0.36787944f};

    for (int s = t; s < P * 9; s += TPB) {
        int p  = s / 9;
        int k  = s - p * 9;
        int dy = k / 3;
        int dx = k - dy * 3;
        float d0 = s_im[dy][p + dx][0] - s_im[1][p + 1][0];
        float d1 = s_im[dy][p + dx][1] - s_im[1][p + 1][1];
        float d2 = s_im[dy][p + dx][2] - s_im[1][p + 1][2];
        float dist2 = d0 * d0 + d1 * d1 + d2 * d2;
        // exp(-dist2 / (2 * 0.25^2)) = exp(-8 * dist2)
        s_w[s] = __expf(-8.0f * dist2) * w1[k];
    }
    __syncthreads();

    // ---- Phase 1c: per-pixel 1/den ----
    if (t < P) {
        float den = 0.f;
        #pragma unroll
        for (int k = 0; k < 9; ++k) den += s_w[t * 9 + k];
        s_invden[t] = 1.0f / den;
    }
    __syncthreads();

    // ---- Phase 2: output, flat over (pixel, channel) for coalescing ----
    const long rowb0 = (long)(b * H + ry0) * W;
    const long rowb1 = (long)(b * H + y  ) * W;
    const long rowb2 = (long)(b * H + ry2) * W;

    for (int e = t; e < P * CS; e += TPB) {
        int p = e / CS;
        int c = e - p * CS;
        int x = x0 + p;
        int xm = reflect1(x - 1, W);
        int xp = reflect1(x + 1, W);
        const float* wp = &s_w[p * 9];
        float acc;
        acc  = src[(rowb0 + xm) * CS + c] * wp[0];
        acc += src[(rowb0 + x ) * CS + c] * wp[1];
        acc += src[(rowb0 + xp) * CS + c] * wp[2];
        acc += src[(rowb1 + xm) * CS + c] * wp[3];
        acc += src[(rowb1 + x ) * CS + c] * wp[4];
        acc += src[(rowb1 + xp) * CS + c] * wp[5];
        acc += src[(rowb2 + xm) * CS + c] * wp[6];
        acc += src[(rowb2 + x ) * CS + c] * wp[7];
        acc += src[(rowb2 + xp) * CS + c] * wp[8];
        out[(rowb1 + x) * CS + c] = acc * s_invden[p];
    }
}

extern "C" void kernel_launch(void* const* d_in, const int* in_sizes, int n_in,
                              void* d_out, int out_size, void* d_ws, size_t ws_size,
                              hipStream_t stream) {
    const float* src = (const float*)d_in[0];
    const float* im  = (const float*)d_in[1];
    float* out = (float*)d_out;
    dim3 grid(W / P, H, BATCH);
    jbu_kernel<<<grid, TPB, 0, stream>>>(src, im, out);
}

// Round 2
// 114.717 us; speedup vs baseline: 1.0993x; 1.0993x over previous
//
#include <hip/hip_runtime.h>

#define BATCH 2
#define H 512
#define W 512
#define CS 21
#define CI 3
#define P 256      // pixels per block (row segment)
#define TPB 256
#define NCH 6      // float4 chunks per pixel, starts {0,4,8,12,16,17}

__device__ __forceinline__ int reflect1(int v, int n) {
    if (v < 0) v = -v;
    else if (v >= n) v = 2 * n - 2 - v;
    return v;
}

__device__ __forceinline__ void fma4(float4& a, const float4 v, const float w) {
    a.x = fmaf(v.x, w, a.x);
    a.y = fmaf(v.y, w, a.y);
    a.z = fmaf(v.z, w, a.z);
    a.w = fmaf(v.w, w, a.w);
}

__global__ __launch_bounds__(TPB) void jbu_kernel(
    const float* __restrict__ src, const float* __restrict__ im,
    float* __restrict__ out)
{
    __shared__ __align__(16) float s_im[3][P + 2][CI];  // 9.3 KB
    __shared__ __align__(16) float s_w[P][12];          // 12 KB, stride 48B keeps float4 reads aligned

    const int t  = threadIdx.x;
    const int x0 = blockIdx.x * P;
    const int y  = blockIdx.y;
    const int b  = blockIdx.z;

    const int ry0 = reflect1(y - 1, H);
    const int ry2 = reflect1(y + 1, H);

    // ---- Phase 1a: stage guide tile (reflect applied at stage time) ----
    for (int i = t; i < 3 * (P + 2) * CI; i += TPB) {
        int r   = i / ((P + 2) * CI);
        int rem = i - r * ((P + 2) * CI);
        int col = rem / CI;
        int ch  = rem - col * CI;
        int ry  = (r == 0) ? ry0 : ((r == 1) ? y : ry2);
        int gx  = reflect1(x0 + col - 1, W);
        s_im[r][col][ch] = im[((b * H + ry) * W + gx) * CI + ch];
    }
    __syncthreads();

    // ---- Phase 1b: per-pixel weights (k is compile-time in unrolled loop),
    //      normalized by 1/den before writing to LDS ----
    {
        const float w1k[9] = {0.36787944f, 0.60653066f, 0.36787944f,
                              0.60653066f, 1.0f,        0.60653066f,
                              0.36787944f, 0.60653066f, 0.36787944f};
        const float c0 = s_im[1][t + 1][0];
        const float c1 = s_im[1][t + 1][1];
        const float c2 = s_im[1][t + 1][2];
        float wv[9];
        float den = 0.f;
        #pragma unroll
        for (int k = 0; k < 9; ++k) {
            const int dy = k / 3, dx = k % 3;
            float d0 = s_im[dy][t + dx][0] - c0;
            float d1 = s_im[dy][t + dx][1] - c1;
            float d2 = s_im[dy][t + dx][2] - c2;
            float w = __expf(-8.0f * (d0 * d0 + d1 * d1 + d2 * d2)) * w1k[k];
            wv[k] = w;
            den += w;
        }
        const float inv = 1.0f / den;
        float4 wa = {wv[0] * inv, wv[1] * inv, wv[2] * inv, wv[3] * inv};
        float4 wb = {wv[4] * inv, wv[5] * inv, wv[6] * inv, wv[7] * inv};
        *(float4*)&s_w[t][0] = wa;
        *(float4*)&s_w[t][4] = wb;
        s_w[t][8] = wv[8] * inv;
    }
    __syncthreads();

    // ---- Phase 2: float4 channel chunks, uniform path (no divergence) ----
    const float* row0 = src + (size_t)(b * H + ry0) * (W * CS);
    const float* row1 = src + (size_t)(b * H + y  ) * (W * CS);
    const float* row2 = src + (size_t)(b * H + ry2) * (W * CS);
    float*       orow = out + (size_t)(b * H + y  ) * (W * CS);

    for (int wi = t; wi < P * NCH; wi += TPB) {   // 1536 items, 6 full iters
        int p = wi / NCH;
        int q = wi - p * NCH;
        int coff = (q == 5) ? 17 : (q << 2);      // chunk starts 0,4,8,12,16,17
        int x  = x0 + p;
        int xm = (x == 0)     ? 1     : x - 1;
        int xp = (x == W - 1) ? W - 2 : x + 1;
        int om = xm * CS + coff;
        int oc = x  * CS + coff;
        int op = xp * CS + coff;

        const float4 wA = *(const float4*)&s_w[p][0];
        const float4 wB = *(const float4*)&s_w[p][4];
        const float  w8 = s_w[p][8];

        float4 v0 = *(const float4*)(row0 + om);
        float4 v1 = *(const float4*)(row0 + oc);
        float4 v2 = *(const float4*)(row0 + op);
        float4 v3 = *(const float4*)(row1 + om);
        float4 v4 = *(const float4*)(row1 + oc);
        float4 v5 = *(const float4*)(row1 + op);
        float4 v6 = *(const float4*)(row2 + om);
        float4 v7 = *(const float4*)(row2 + oc);
        float4 v8 = *(const float4*)(row2 + op);

        float4 acc = {0.f, 0.f, 0.f, 0.f};
        fma4(acc, v0, wA.x);
        fma4(acc, v1, wA.y);
        fma4(acc, v2, wA.z);
        fma4(acc, v3, wA.w);
        fma4(acc, v4, wB.x);
        fma4(acc, v5, wB.y);
        fma4(acc, v6, wB.z);
        fma4(acc, v7, wB.w);
        fma4(acc, v8, w8);

        *(float4*)(orow + oc) = acc;
    }
}

extern "C" void kernel_launch(void* const* d_in, const int* in_sizes, int n_in,
                              void* d_out, int out_size, void* d_ws, size_t ws_size,
                              hipStream_t stream) {
    const float* src = (const float*)d_in[0];
    const float* im  = (const float*)d_in[1];
    float* out = (float*)d_out;
    dim3 grid(W / P, H, BATCH);
    jbu_kernel<<<grid, TPB, 0, stream>>>(src, im, out);
}

// Round 3
// 112.600 us; speedup vs baseline: 1.1200x; 1.0188x over previous
//
#include <hip/hip_runtime.h>

#define BATCH 2
#define H 512
#define W 512
#define CS 21
#define CI 3
#define P 256      // pixels per block (row segment)
#define TPB 256
#define NCH 6      // float4 chunks per pixel, starts {0,4,8,12,16,17}

__device__ __forceinline__ void fma4(float4& a, const float4 v, const float w) {
    a.x = fmaf(v.x, w, a.x);
    a.y = fmaf(v.y, w, a.y);
    a.z = fmaf(v.z, w, a.z);
    a.w = fmaf(v.w, w, a.w);
}

// LDS: single 12 KB buffer. Phase 1 uses first 2322 floats as guide tile
// [3][P+2][3]; after weights are computed into registers it is overwritten
// with the per-pixel normalized weights [P][12] (stride 12 keeps float4
// reads 16B-aligned at offsets 0 and 4).
__global__ __launch_bounds__(TPB, 8) void jbu_kernel(
    const float* __restrict__ src, const float* __restrict__ im,
    float* __restrict__ out)
{
    __shared__ __align__(16) float s_buf[P * 12];   // 12 KB

    const int t = threadIdx.x;

    // ---- XCD-aware swizzle: XCD (f&7) owns contiguous 64-row band ----
    // order within an XCD: row fastest, then x-segment, then batch
    const int f   = blockIdx.x;          // 0..2047
    const int xcd = f & 7;
    const int g   = f >> 3;              // 0..255
    const int y   = (xcd << 6) | (g & 63);
    const int r   = g >> 6;              // 0..3
    const int x0  = (r & 1) * P;
    const int b   = r >> 1;

    const int ry0 = (y == 0)     ? 1     : y - 1;
    const int ry2 = (y == H - 1) ? H - 2 : y + 1;

    // ---- Phase 1a: stage guide tile (reflect applied at stage time) ----
    const float* imb = im + (size_t)b * H * W * CI;
    for (int i = t; i < 3 * (P + 2) * CI; i += TPB) {
        int row = i / ((P + 2) * CI);
        int rem = i - row * ((P + 2) * CI);
        int col = rem / CI;
        int ch  = rem - col * CI;
        int ry  = (row == 0) ? ry0 : ((row == 1) ? y : ry2);
        int gx  = x0 + col - 1;
        gx = (gx < 0) ? 1 : ((gx >= W) ? W - 2 : gx);
        s_buf[i] = imb[(ry * W + gx) * CI + ch];
    }
    __syncthreads();

    // ---- Phase 1b: per-pixel weights in registers, normalized ----
    float4 wa, wb;
    float w8n;
    {
        const float w1k[9] = {0.36787944f, 0.60653066f, 0.36787944f,
                              0.60653066f, 1.0f,        0.60653066f,
                              0.36787944f, 0.60653066f, 0.36787944f};
        const int cbase = ((P + 2) + t + 1) * CI;   // center pixel, middle row
        const float c0 = s_buf[cbase + 0];
        const float c1 = s_buf[cbase + 1];
        const float c2 = s_buf[cbase + 2];
        float wv[9];
        float den = 0.f;
        #pragma unroll
        for (int k = 0; k < 9; ++k) {
            const int dy = k / 3, dx = k % 3;
            const int idx = (dy * (P + 2) + t + dx) * CI;
            float d0 = s_buf[idx + 0] - c0;
            float d1 = s_buf[idx + 1] - c1;
            float d2 = s_buf[idx + 2] - c2;
            float w = __expf(-8.0f * (d0 * d0 + d1 * d1 + d2 * d2)) * w1k[k];
            wv[k] = w;
            den += w;
        }
        const float inv = 1.0f / den;
        wa = make_float4(wv[0] * inv, wv[1] * inv, wv[2] * inv, wv[3] * inv);
        wb = make_float4(wv[4] * inv, wv[5] * inv, wv[6] * inv, wv[7] * inv);
        w8n = wv[8] * inv;
    }
    __syncthreads();   // all reads of guide tile done before overwrite

    *(float4*)&s_buf[t * 12 + 0] = wa;
    *(float4*)&s_buf[t * 12 + 4] = wb;
    s_buf[t * 12 + 8] = w8n;
    __syncthreads();

    // ---- Phase 2: float4 channel chunks, uniform path ----
    const float* row0 = src + (size_t)(b * H + ry0) * (W * CS);
    const float* row1 = src + (size_t)(b * H + y  ) * (W * CS);
    const float* row2 = src + (size_t)(b * H + ry2) * (W * CS);
    float*       orow = out + (size_t)(b * H + y  ) * (W * CS);

    for (int wi = t; wi < P * NCH; wi += TPB) {   // exactly 6 iterations
        int p = wi / NCH;
        int q = wi - p * NCH;
        int coff = (q == 5) ? 17 : (q << 2);      // chunk starts 0,4,8,12,16,17
        int x  = x0 + p;
        int xm = (x == 0)     ? 1     : x - 1;
        int xp = (x == W - 1) ? W - 2 : x + 1;
        int om = xm * CS + coff;
        int oc = x  * CS + coff;
        int op = xp * CS + coff;

        const float4 pwA = *(const float4*)&s_buf[p * 12 + 0];
        const float4 pwB = *(const float4*)&s_buf[p * 12 + 4];
        const float  pw8 = s_buf[p * 12 + 8];

        float4 v0 = *(const float4*)(row0 + om);
        float4 v1 = *(const float4*)(row0 + oc);
        float4 v2 = *(const float4*)(row0 + op);
        float4 v3 = *(const float4*)(row1 + om);
        float4 v4 = *(const float4*)(row1 + oc);
        float4 v5 = *(const float4*)(row1 + op);
        float4 v6 = *(const float4*)(row2 + om);
        float4 v7 = *(const float4*)(row2 + oc);
        float4 v8 = *(const float4*)(row2 + op);

        float4 acc = {0.f, 0.f, 0.f, 0.f};
        fma4(acc, v0, pwA.x);
        fma4(acc, v1, pwA.y);
        fma4(acc, v2, pwA.z);
        fma4(acc, v3, pwA.w);
        fma4(acc, v4, pwB.x);
        fma4(acc, v5, pwB.y);
        fma4(acc, v6, pwB.z);
        fma4(acc, v7, pwB.w);
        fma4(acc, v8, pw8);

        *(float4*)(orow + oc) = acc;
    }
}

extern "C" void kernel_launch(void* const* d_in, const int* in_sizes, int n_in,
                              void* d_out, int out_size, void* d_ws, size_t ws_size,
                              hipStream_t stream) {
    const float* src = (const float*)d_in[0];
    const float* im  = (const float*)d_in[1];
    float* out = (float*)d_out;
    dim3 grid((W / P) * H * BATCH, 1, 1);   // 2048 blocks, swizzle-decoded in-kernel
    jbu_kernel<<<grid, TPB, 0, stream>>>(src, im, out);
}